// Round 6
// baseline (186.272 us; speedup 1.0000x reference)
//
#include <hip/hip_runtime.h>
#include <math.h>

#define NP 50000
#define HIDDEN 256
#define NE 800000
#define CAP 64          // ELL capacity; P(Poisson(16) > 64) ~ 1e-20

// workspace layout (bytes)
// AH / A2H stored feature-split: [2][P][128] bf16 (half-feature planes)
#define OFF_AH     0ULL           // [2][P][128] bf16 : AH
#define OFF_A2H    25600000ULL    // [2][P][128] bf16 : A2H
#define OFF_BP     51200000ULL    // Bp [64][256][8] bf16 packed weights
#define OFF_CNT    51462144ULL    // per-row edge count [P] int
#define OFF_PC     51662144ULL    // packed (beta,degree) [P] float2
#define OFF_EV     52062144ULL    // ELL edges (col, val-bits) [P][CAP] int2

#define HPLANE (NP * 128)         // elements per half-feature plane

typedef __attribute__((ext_vector_type(8))) short bf16x8;
typedef __attribute__((ext_vector_type(8))) unsigned short u16x8;
typedef __attribute__((ext_vector_type(4))) float f32x4;

__device__ inline unsigned short f2bf(float f) {
    union { float f; unsigned int u; } x; x.f = f;
    unsigned int r = x.u + 0x7FFFu + ((x.u >> 16) & 1u);   // RNE
    return (unsigned short)(r >> 16);
}
__device__ inline float bf2f(unsigned short u) {
    union { unsigned int u; float f; } x; x.u = ((unsigned int)u) << 16; return x.f;
}

// ---------------- pack weights: Bp[k>>3][col][k&7] = Wcat[col][k], bf16 ----------------
__global__ void bp_kernel(const float* __restrict__ W1,
                          const float* __restrict__ W2,
                          unsigned short* __restrict__ Bp) {
    int t = blockIdx.x * 256 + threadIdx.x;   // 512*256
    int j = t >> 9;
    int k = t & 511;
    float v = (k < 256) ? W1[j * 256 + k] : W2[j * 256 + (k - 256)];
    Bp[(k >> 3) * 2048 + j * 8 + (k & 7)] = f2bf(v);
}

// ---------------- pack (beta, degree) ----------------
__global__ void pc_kernel(const float* __restrict__ beta,
                          const float* __restrict__ degree,
                          float2* __restrict__ pc) {
    int i = blockIdx.x * 256 + threadIdx.x;
    if (i < NP) pc[i] = make_float2(beta[i], degree[i]);
}

// ---------------- ELL scatter (cnt must be zeroed) ----------------
__global__ void scatter_ell(const int* __restrict__ rows,
                            const int* __restrict__ cols,
                            const float* __restrict__ vals,
                            int* __restrict__ cnt,
                            int2* __restrict__ ev) {
    int e = blockIdx.x * 256 + threadIdx.x;
    if (e < NE) {
        int r = rows[e];
        int pos = atomicAdd(&cnt[r], 1);
        if (pos < CAP)
            ev[(size_t)r * CAP + pos] = make_int2(cols[e], __float_as_int(vals[e]));
    }
}

// ---------------- hop 1 fused: AH[r] = sum_e val * relu(W_in . x[col] + b_in) ----------------
// wave per row; halves process 2 edges concurrently; writes split layout
__global__ __launch_bounds__(256) void spmm_embed_kernel(
        const int* __restrict__ cnt, const int2* __restrict__ ev,
        const float2* __restrict__ pc,
        const float* __restrict__ W_in, const float* __restrict__ b_in,
        unsigned short* __restrict__ Y) {
    int w = threadIdx.x >> 6;
    int lane = threadIdx.x & 63;
    int r = blockIdx.x * 4 + w;
    if (r >= NP) return;
    int half = lane >> 5;
    int fo = (lane & 31) * 8;

    int n = min(cnt[r], CAP);
    int2 e2 = make_int2(0, 0);                 // val 0 beyond n -> padded steps harmless
    if (lane < n) e2 = ev[(size_t)r * CAP + lane];
    int col_l = e2.x;
    float val_l = __int_as_float(e2.y);

    float wr0[8], wr1[8], wr2[8], br[8];
    #pragma unroll
    for (int j = 0; j < 8; ++j) {
        wr0[j] = W_in[(fo + j) * 3 + 0];
        wr1[j] = W_in[(fo + j) * 3 + 1];
        wr2[j] = W_in[(fo + j) * 3 + 2];
        br[j]  = b_in[fo + j];
    }

    float acc[8] = {0.f,0.f,0.f,0.f,0.f,0.f,0.f,0.f};

#define ESTEP(d)                                                             \
    {                                                                        \
        float2 pr[d]; float vr[d];                                           \
        _Pragma("unroll")                                                    \
        for (int k = 0; k < (d); ++k) {                                      \
            int e = i + 2 * k + half;                                        \
            int c = __shfl(col_l, e);                                        \
            vr[k] = __shfl(val_l, e);                                        \
            pr[k] = pc[c];                                                   \
        }                                                                    \
        _Pragma("unroll")                                                    \
        for (int k = 0; k < (d); ++k) {                                      \
            float b = pr[k].x, dd = pr[k].y, v = vr[k];                      \
            float b2 = b * b;                                                \
            _Pragma("unroll")                                                \
            for (int j = 0; j < 8; ++j) {                                    \
                float t = fmaf(b, wr0[j], fmaf(b2, wr1[j], fmaf(dd, wr2[j], br[j]))); \
                acc[j] = fmaf(v, fmaxf(t, 0.f), acc[j]);                     \
            }                                                                \
        }                                                                    \
    }

    int i = 0;
    for (; i + 16 <= n; i += 16) ESTEP(8)
    if (i + 8 <= n) { ESTEP(4) i += 8; }
    if (i + 4 <= n) { ESTEP(2) i += 4; }
    if (i < n)      { ESTEP(2) }          // i % 4 == 0, i <= 60 -> shuffle lane <= 63
#undef ESTEP

    #pragma unroll
    for (int j = 0; j < 8; ++j) acc[j] += __shfl_xor(acc[j], 32);
    if (half == 0) {
        u16x8 o;
        #pragma unroll
        for (int j = 0; j < 8; ++j) o[j] = f2bf(acc[j]);
        int f = fo >> 7;                  // which half-feature plane
        int off = fo & 127;
        *reinterpret_cast<u16x8*>(Y + (size_t)f * HPLANE + (size_t)r * 128 + off) = o;
    }
}

// ---------------- hop 2: half-feature gather SpMM ----------------
// quarter-wave (16 lanes) per edge: 4 edges/instr, 16B/lane; X,Y are [P][128] planes
__global__ __launch_bounds__(256) void spmm_gather_half(
        const int* __restrict__ cnt, const int2* __restrict__ ev,
        const unsigned short* __restrict__ X,
        unsigned short* __restrict__ Y) {
    int w = threadIdx.x >> 6;
    int lane = threadIdx.x & 63;
    int r = blockIdx.x * 4 + w;
    if (r >= NP) return;
    int q = lane >> 4;            // quarter 0..3
    int fo = (lane & 15) * 8;     // 0..120

    int n = min(cnt[r], CAP);
    int2 e2 = make_int2(0, 0);
    if (lane < n) e2 = ev[(size_t)r * CAP + lane];
    int col_l = e2.x;
    float val_l = __int_as_float(e2.y);

    float acc[8] = {0.f,0.f,0.f,0.f,0.f,0.f,0.f,0.f};

#define GS(d, MASKED)                                                        \
    {                                                                        \
        u16x8 xr[d]; float vr[d];                                            \
        _Pragma("unroll")                                                    \
        for (int k = 0; k < (d); ++k) {                                      \
            int e = i + 4 * k + q;                                           \
            int es = (MASKED) ? (e & 63) : e;                                \
            int c = __shfl(col_l, es);                                       \
            float vt = __shfl(val_l, es);                                    \
            if (MASKED) vt = (e < n) ? vt : 0.f;                             \
            vr[k] = vt;                                                      \
            xr[k] = *reinterpret_cast<const u16x8*>(X + (size_t)c * 128 + fo); \
        }                                                                    \
        _Pragma("unroll")                                                    \
        for (int k = 0; k < (d); ++k)                                        \
            _Pragma("unroll")                                                \
            for (int j = 0; j < 8; ++j)                                      \
                acc[j] = fmaf(vr[k], bf2f(xr[k][j]), acc[j]);                \
    }

    int i = 0;
    for (; i + 32 <= n; i += 32) GS(8, false)
    if (i + 16 <= n) { GS(4, false) i += 16; }
    if (i + 8 <= n)  { GS(2, false) i += 8; }
    if (i < n)       { GS(2, true) }       // remaining <= 7 edges, masked
#undef GS

    #pragma unroll
    for (int j = 0; j < 8; ++j) {
        acc[j] += __shfl_xor(acc[j], 16);
        acc[j] += __shfl_xor(acc[j], 32);
    }
    if (q == 0) {
        u16x8 o;
        #pragma unroll
        for (int j = 0; j < 8; ++j) o[j] = f2bf(acc[j]);
        *reinterpret_cast<u16x8*>(Y + (size_t)r * 128 + fo) = o;
    }
}

// ---------------- fused MP GEMM (MFMA bf16) + relu + out-proj + softplus ----------------
// block: 512 threads = 8 waves; tile 128 rows x 256 cols; K = 512 in 8 chunks of 64
// K-chunks 0..3 read AH planes, 4..7 read A2H planes (split [2][P][128] layout)
__global__ __launch_bounds__(512, 4) void mp_out_kernel(
        const unsigned short* __restrict__ AH,
        const unsigned short* __restrict__ A2H,
        const unsigned short* __restrict__ Bp,
        const float* __restrict__ W_out, const float* __restrict__ b_out,
        float* __restrict__ g) {
    __shared__ unsigned short As[128 * 64];    // 16 KB, XOR-swizzled
    __shared__ unsigned short Bs[8 * 256 * 8]; // 32 KB, [kbl][col][8]
    __shared__ float Ps[4][128];               // 2 KB partials

    int tid = threadIdx.x;
    int w = tid >> 6;
    int lane = tid & 63;
    int wr = w >> 2;
    int wc = w & 3;
    int p0 = blockIdx.x * 128;

    f32x4 acc[4][4];
    #pragma unroll
    for (int i = 0; i < 4; ++i)
        #pragma unroll
        for (int j = 0; j < 4; ++j)
            acc[i][j] = (f32x4){0.f, 0.f, 0.f, 0.f};

    for (int kc = 0; kc < 8; ++kc) {
        const unsigned short* Xb = (kc < 4) ? AH : A2H;
        int kcl = kc & 3;
        const unsigned short* Xsrc = Xb + (size_t)(kcl >> 1) * HPLANE;
        int k0h = (kcl & 1) * 64;
        __syncthreads();
        // stage A: 1024 x 16B slots. LDS[slot] = A_global[slot ^ swz(row)] (both-sides swizzle)
        #pragma unroll
        for (int it = 0; it < 2; ++it) {
            int slot = it * 512 + tid;
            int ss = slot ^ ((slot >> 3) & 7);         // involution, row bits untouched
            int row = ss >> 3;
            int ko = (ss & 7) * 8;
            int grow = p0 + row;
            if (grow >= NP) grow = NP - 1;
            float4 v = *reinterpret_cast<const float4*>(Xsrc + (size_t)grow * 128 + k0h + ko);
            *reinterpret_cast<float4*>(&As[slot * 8]) = v;
        }
        // stage B: 2048 x 16B chunks, linear
        #pragma unroll
        for (int it = 0; it < 4; ++it) {
            int c2 = it * 512 + tid;
            float4 v = *reinterpret_cast<const float4*>(
                Bp + ((size_t)(kc * 8 + (c2 >> 8))) * 2048 + (c2 & 255) * 8);
            *reinterpret_cast<float4*>(&Bs[c2 * 8]) = v;
        }
        __syncthreads();
        #pragma unroll
        for (int ks = 0; ks < 2; ++ks) {
            bf16x8 af[4], bfr[4];
            #pragma unroll
            for (int rt = 0; rt < 4; ++rt) {
                int row = wr * 64 + rt * 16 + (lane & 15);
                int elem = row * 64 + ks * 32 + (lane >> 4) * 8;
                elem ^= (row & 7) << 3;                // matches staging swizzle
                af[rt] = *reinterpret_cast<const bf16x8*>(&As[elem]);
            }
            #pragma unroll
            for (int nt = 0; nt < 4; ++nt) {
                int col = wc * 64 + nt * 16 + (lane & 15);
                int kbl = ks * 4 + (lane >> 4);
                bfr[nt] = *reinterpret_cast<const bf16x8*>(&Bs[kbl * 2048 + col * 8]);
            }
            #pragma unroll
            for (int rt = 0; rt < 4; ++rt)
                #pragma unroll
                for (int nt = 0; nt < 4; ++nt)
                    acc[rt][nt] = __builtin_amdgcn_mfma_f32_16x16x32_bf16(
                        af[rt], bfr[nt], acc[rt][nt], 0, 0, 0);
        }
    }

    // epilogue: relu -> dot W_out (this wave's 64 cols) -> LDS partial
    float wv[4];
    #pragma unroll
    for (int nt = 0; nt < 4; ++nt)
        wv[nt] = W_out[wc * 64 + nt * 16 + (lane & 15)];

    float ps[4][4];
    #pragma unroll
    for (int rt = 0; rt < 4; ++rt)
        #pragma unroll
        for (int r = 0; r < 4; ++r) {
            float s = 0.f;
            #pragma unroll
            for (int nt = 0; nt < 4; ++nt)
                s = fmaf(fmaxf(acc[rt][nt][r], 0.0f), wv[nt], s);
            ps[rt][r] = s;
        }
    #pragma unroll
    for (int m = 1; m < 16; m <<= 1)
        #pragma unroll
        for (int rt = 0; rt < 4; ++rt)
            #pragma unroll
            for (int r = 0; r < 4; ++r)
                ps[rt][r] += __shfl_xor(ps[rt][r], m);

    if ((lane & 15) == 0) {
        int rb = wr * 64 + (lane >> 4) * 4;
        #pragma unroll
        for (int rt = 0; rt < 4; ++rt)
            #pragma unroll
            for (int r = 0; r < 4; ++r)
                Ps[wc][rb + rt * 16 + r] = ps[rt][r];
    }
    __syncthreads();
    if (tid < 128) {
        int p = p0 + tid;
        if (p < NP) {
            float z = Ps[0][tid] + Ps[1][tid] + Ps[2][tid] + Ps[3][tid] + b_out[0];
            g[p] = fmaxf(z, 0.0f) + log1pf(expf(-fabsf(z)));
        }
    }
}

extern "C" void kernel_launch(void* const* d_in, const int* in_sizes, int n_in,
                              void* d_out, int out_size, void* d_ws, size_t ws_size,
                              hipStream_t stream) {
    const float* beta   = (const float*)d_in[0];
    const float* degree = (const float*)d_in[1];
    const int*   A_rows = (const int*)d_in[2];
    const int*   A_cols = (const int*)d_in[3];
    const float* A_vals = (const float*)d_in[4];
    const float* W_in   = (const float*)d_in[5];
    const float* b_in   = (const float*)d_in[6];
    const float* W_mp1  = (const float*)d_in[7];
    const float* W_mp2  = (const float*)d_in[8];
    const float* W_out  = (const float*)d_in[9];
    const float* b_out  = (const float*)d_in[10];
    float* g = (float*)d_out;

    char* ws = (char*)d_ws;
    unsigned short* AH  = (unsigned short*)(ws + OFF_AH);
    unsigned short* A2H = (unsigned short*)(ws + OFF_A2H);
    unsigned short* Bp  = (unsigned short*)(ws + OFF_BP);
    int*    cnt = (int*)(ws + OFF_CNT);
    float2* pc  = (float2*)(ws + OFF_PC);
    int2*   ev  = (int2*)(ws + OFF_EV);

    hipMemsetAsync(cnt, 0, NP * sizeof(int), stream);

    bp_kernel<<<512, 256, 0, stream>>>(W_mp1, W_mp2, Bp);
    pc_kernel<<<(NP + 255) / 256, 256, 0, stream>>>(beta, degree, pc);

    scatter_ell<<<(NE + 255) / 256, 256, 0, stream>>>(A_rows, A_cols, A_vals, cnt, ev);

    // AH = A @ relu(x W_in^T + b_in)   (h recomputed per edge, split planes)
    spmm_embed_kernel<<<(NP + 3) / 4, 256, 0, stream>>>(cnt, ev, pc, W_in, b_in, AH);

    // A2H = A @ AH, one pass per half-feature plane (12.8 MB working set each)
    spmm_gather_half<<<(NP + 3) / 4, 256, 0, stream>>>(cnt, ev, AH, A2H);
    spmm_gather_half<<<(NP + 3) / 4, 256, 0, stream>>>(cnt, ev, AH + HPLANE, A2H + HPLANE);

    mp_out_kernel<<<(NP + 127) / 128, 512, 0, stream>>>(AH, A2H, Bp, W_out, b_out, g);
}

// Round 7
// 171.067 us; speedup vs baseline: 1.0889x; 1.0889x over previous
//
#include <hip/hip_runtime.h>
#include <math.h>

#define NP 50000
#define HIDDEN 256
#define NE 800000
#define CAP 64          // ELL capacity; P(Poisson(16) > 64) ~ 1e-20

#define NSLICE 8
#define SLICE_ROWS 6250            // NP / NSLICE
#define BPS 256                    // blocks per slice

// workspace layout (bytes)
#define OFF_AH     0ULL           // [P][256] bf16 : AH
#define OFF_A2H    25600000ULL    // [P][256] bf16 : A2H
#define OFF_BP     51200000ULL    // Bp [64][256][8] bf16 packed weights
#define OFF_CNT    51462144ULL    // per-row edge count [P] int
#define OFF_PC     51662144ULL    // packed (beta,degree) [P] float2
#define OFF_EV     52062144ULL    // ELL edges (col, val-bits) [P][CAP] int2

typedef __attribute__((ext_vector_type(8))) short bf16x8;
typedef __attribute__((ext_vector_type(8))) unsigned short u16x8;
typedef __attribute__((ext_vector_type(4))) float f32x4;

__device__ inline unsigned short f2bf(float f) {
    union { float f; unsigned int u; } x; x.f = f;
    unsigned int r = x.u + 0x7FFFu + ((x.u >> 16) & 1u);   // RNE
    return (unsigned short)(r >> 16);
}
__device__ inline float bf2f(unsigned short u) {
    union { unsigned int u; float f; } x; x.u = ((unsigned int)u) << 16; return x.f;
}

// ---------------- pack weights: Bp[k>>3][col][k&7] = Wcat[col][k], bf16 ----------------
__global__ void bp_kernel(const float* __restrict__ W1,
                          const float* __restrict__ W2,
                          unsigned short* __restrict__ Bp) {
    int t = blockIdx.x * 256 + threadIdx.x;   // 512*256
    int j = t >> 9;
    int k = t & 511;
    float v = (k < 256) ? W1[j * 256 + k] : W2[j * 256 + (k - 256)];
    Bp[(k >> 3) * 2048 + j * 8 + (k & 7)] = f2bf(v);
}

// ---------------- pack (beta, degree) ----------------
__global__ void pc_kernel(const float* __restrict__ beta,
                          const float* __restrict__ degree,
                          float2* __restrict__ pc) {
    int i = blockIdx.x * 256 + threadIdx.x;
    if (i < NP) pc[i] = make_float2(beta[i], degree[i]);
}

// ---------------- XCD-sliced ELL scatter (cnt must be zeroed) ----------------
// slice = blockIdx % 8 -> dispatch round-robin puts each slice on one XCD (perf
// heuristic only; correct under any mapping). Slice's ev region = 3.2 MB, fits
// that XCD's L2 -> edge writes coalesce into full lines before writeback.
__global__ __launch_bounds__(256) void scatter_sliced(
        const int* __restrict__ rows, const int* __restrict__ cols,
        const float* __restrict__ vals,
        int* __restrict__ cnt, int2* __restrict__ ev) {
    int slice = blockIdx.x & (NSLICE - 1);
    int bj = blockIdx.x >> 3;
    int rlo = slice * SLICE_ROWS;
    int rhi = rlo + SLICE_ROWS;
    for (int e = bj * 256 + threadIdx.x; e < NE; e += BPS * 256) {
        int r = rows[e];
        if (r >= rlo && r < rhi) {
            int pos = atomicAdd(&cnt[r], 1);
            if (pos < CAP)
                ev[(size_t)r * CAP + pos] = make_int2(cols[e], __float_as_int(vals[e]));
        }
    }
}

// ---------------- hop 1 fused: AH[r] = sum_e val * relu(W_in . x[col] + b_in) ----------------
// wave per row; edges preloaded one per lane (zero-padded past n); adaptive depth ladder
__global__ __launch_bounds__(256) void spmm_embed_kernel(
        const int* __restrict__ cnt, const int2* __restrict__ ev,
        const float2* __restrict__ pc,
        const float* __restrict__ W_in, const float* __restrict__ b_in,
        unsigned short* __restrict__ Y) {
    int w = threadIdx.x >> 6;
    int lane = threadIdx.x & 63;
    int r = blockIdx.x * 4 + w;
    if (r >= NP) return;
    int half = lane >> 5;
    int fo = (lane & 31) * 8;

    int n = min(cnt[r], CAP);
    int2 e2 = make_int2(0, 0);                 // val 0 beyond n -> padded steps harmless
    if (lane < n) e2 = ev[(size_t)r * CAP + lane];
    int col_l = e2.x;
    float val_l = __int_as_float(e2.y);

    float wr0[8], wr1[8], wr2[8], br[8];
    #pragma unroll
    for (int j = 0; j < 8; ++j) {
        wr0[j] = W_in[(fo + j) * 3 + 0];
        wr1[j] = W_in[(fo + j) * 3 + 1];
        wr2[j] = W_in[(fo + j) * 3 + 2];
        br[j]  = b_in[fo + j];
    }

    float acc[8] = {0.f,0.f,0.f,0.f,0.f,0.f,0.f,0.f};

#define ESTEP(d)                                                             \
    {                                                                        \
        float2 pr[d]; float vr[d];                                           \
        _Pragma("unroll")                                                    \
        for (int k = 0; k < (d); ++k) {                                      \
            int e = i + 2 * k + half;                                        \
            int c = __shfl(col_l, e);                                        \
            vr[k] = __shfl(val_l, e);                                        \
            pr[k] = pc[c];                                                   \
        }                                                                    \
        _Pragma("unroll")                                                    \
        for (int k = 0; k < (d); ++k) {                                      \
            float b = pr[k].x, dd = pr[k].y, v = vr[k];                      \
            float b2 = b * b;                                                \
            _Pragma("unroll")                                                \
            for (int j = 0; j < 8; ++j) {                                    \
                float t = fmaf(b, wr0[j], fmaf(b2, wr1[j], fmaf(dd, wr2[j], br[j]))); \
                acc[j] = fmaf(v, fmaxf(t, 0.f), acc[j]);                     \
            }                                                                \
        }                                                                    \
    }

    int i = 0;
    for (; i + 16 <= n; i += 16) ESTEP(8)
    if (i + 8 <= n) { ESTEP(4) i += 8; }
    if (i + 4 <= n) { ESTEP(2) i += 4; }
    if (i < n)      { ESTEP(2) }          // i % 4 == 0, i <= 60 -> shuffle lane <= 63
#undef ESTEP

    #pragma unroll
    for (int j = 0; j < 8; ++j) acc[j] += __shfl_xor(acc[j], 32);
    if (half == 0) {
        u16x8 o;
        #pragma unroll
        for (int j = 0; j < 8; ++j) o[j] = f2bf(acc[j]);
        *reinterpret_cast<u16x8*>(Y + (size_t)r * HIDDEN + fo) = o;
    }
}

// ---------------- hop 2: gather SpMM, adaptive depth ladder ----------------
__global__ __launch_bounds__(256) void spmm_gather_kernel(
        const int* __restrict__ cnt, const int2* __restrict__ ev,
        const unsigned short* __restrict__ X,
        unsigned short* __restrict__ Y) {
    int w = threadIdx.x >> 6;
    int lane = threadIdx.x & 63;
    int r = blockIdx.x * 4 + w;
    if (r >= NP) return;
    int half = lane >> 5;
    int fo = (lane & 31) * 8;

    int n = min(cnt[r], CAP);
    int2 e2 = make_int2(0, 0);
    if (lane < n) e2 = ev[(size_t)r * CAP + lane];
    int col_l = e2.x;
    float val_l = __int_as_float(e2.y);

    float acc[8] = {0.f,0.f,0.f,0.f,0.f,0.f,0.f,0.f};

#define GSTEP(d)                                                             \
    {                                                                        \
        u16x8 xr[d]; float vr[d];                                            \
        _Pragma("unroll")                                                    \
        for (int k = 0; k < (d); ++k) {                                      \
            int e = i + 2 * k + half;                                        \
            int c = __shfl(col_l, e);                                        \
            vr[k] = __shfl(val_l, e);                                        \
            xr[k] = *reinterpret_cast<const u16x8*>(X + (size_t)c * HIDDEN + fo); \
        }                                                                    \
        _Pragma("unroll")                                                    \
        for (int k = 0; k < (d); ++k)                                        \
            _Pragma("unroll")                                                \
            for (int j = 0; j < 8; ++j)                                      \
                acc[j] = fmaf(vr[k], bf2f(xr[k][j]), acc[j]);                \
    }

    int i = 0;
    for (; i + 16 <= n; i += 16) GSTEP(8)
    if (i + 8 <= n) { GSTEP(4) i += 8; }
    if (i + 4 <= n) { GSTEP(2) i += 4; }
    if (i < n)      { GSTEP(2) }
#undef GSTEP

    #pragma unroll
    for (int j = 0; j < 8; ++j) acc[j] += __shfl_xor(acc[j], 32);
    if (half == 0) {
        u16x8 o;
        #pragma unroll
        for (int j = 0; j < 8; ++j) o[j] = f2bf(acc[j]);
        *reinterpret_cast<u16x8*>(Y + (size_t)r * HIDDEN + fo) = o;
    }
}

// ---------------- fused MP GEMM (MFMA bf16) + relu + out-proj + softplus ----------------
// block: 512 threads = 8 waves; tile 128 rows x 256 cols; K = 512 in 8 chunks of 64
// K-chunks 0..3 read AH, 4..7 read A2H (both compact [P][256])
__global__ __launch_bounds__(512, 4) void mp_out_kernel(
        const unsigned short* __restrict__ AH,
        const unsigned short* __restrict__ A2H,
        const unsigned short* __restrict__ Bp,
        const float* __restrict__ W_out, const float* __restrict__ b_out,
        float* __restrict__ g) {
    __shared__ unsigned short As[128 * 64];    // 16 KB, XOR-swizzled
    __shared__ unsigned short Bs[8 * 256 * 8]; // 32 KB, [kbl][col][8]
    __shared__ float Ps[4][128];               // 2 KB partials

    int tid = threadIdx.x;
    int w = tid >> 6;
    int lane = tid & 63;
    int wr = w >> 2;
    int wc = w & 3;
    int p0 = blockIdx.x * 128;

    f32x4 acc[4][4];
    #pragma unroll
    for (int i = 0; i < 4; ++i)
        #pragma unroll
        for (int j = 0; j < 4; ++j)
            acc[i][j] = (f32x4){0.f, 0.f, 0.f, 0.f};

    for (int kc = 0; kc < 8; ++kc) {
        const unsigned short* Xsrc = (kc < 4) ? AH : A2H;
        int k0 = (kc & 3) * 64;
        __syncthreads();
        // stage A: 1024 x 16B slots. LDS[slot] = A_global[slot ^ swz(row)] (both-sides swizzle)
        #pragma unroll
        for (int it = 0; it < 2; ++it) {
            int slot = it * 512 + tid;
            int ss = slot ^ ((slot >> 3) & 7);         // involution, row bits untouched
            int row = ss >> 3;
            int ko = (ss & 7) * 8;
            int grow = p0 + row;
            if (grow >= NP) grow = NP - 1;
            float4 v = *reinterpret_cast<const float4*>(Xsrc + (size_t)grow * HIDDEN + k0 + ko);
            *reinterpret_cast<float4*>(&As[slot * 8]) = v;
        }
        // stage B: 2048 x 16B chunks, linear
        #pragma unroll
        for (int it = 0; it < 4; ++it) {
            int c2 = it * 512 + tid;
            float4 v = *reinterpret_cast<const float4*>(
                Bp + ((size_t)(kc * 8 + (c2 >> 8))) * 2048 + (c2 & 255) * 8);
            *reinterpret_cast<float4*>(&Bs[c2 * 8]) = v;
        }
        __syncthreads();
        #pragma unroll
        for (int ks = 0; ks < 2; ++ks) {
            bf16x8 af[4], bfr[4];
            #pragma unroll
            for (int rt = 0; rt < 4; ++rt) {
                int row = wr * 64 + rt * 16 + (lane & 15);
                int elem = row * 64 + ks * 32 + (lane >> 4) * 8;
                elem ^= (row & 7) << 3;                // matches staging swizzle
                af[rt] = *reinterpret_cast<const bf16x8*>(&As[elem]);
            }
            #pragma unroll
            for (int nt = 0; nt < 4; ++nt) {
                int col = wc * 64 + nt * 16 + (lane & 15);
                int kbl = ks * 4 + (lane >> 4);
                bfr[nt] = *reinterpret_cast<const bf16x8*>(&Bs[kbl * 2048 + col * 8]);
            }
            #pragma unroll
            for (int rt = 0; rt < 4; ++rt)
                #pragma unroll
                for (int nt = 0; nt < 4; ++nt)
                    acc[rt][nt] = __builtin_amdgcn_mfma_f32_16x16x32_bf16(
                        af[rt], bfr[nt], acc[rt][nt], 0, 0, 0);
        }
    }

    // epilogue: relu -> dot W_out (this wave's 64 cols) -> LDS partial
    float wv[4];
    #pragma unroll
    for (int nt = 0; nt < 4; ++nt)
        wv[nt] = W_out[wc * 64 + nt * 16 + (lane & 15)];

    float ps[4][4];
    #pragma unroll
    for (int rt = 0; rt < 4; ++rt)
        #pragma unroll
        for (int r = 0; r < 4; ++r) {
            float s = 0.f;
            #pragma unroll
            for (int nt = 0; nt < 4; ++nt)
                s = fmaf(fmaxf(acc[rt][nt][r], 0.0f), wv[nt], s);
            ps[rt][r] = s;
        }
    #pragma unroll
    for (int m = 1; m < 16; m <<= 1)
        #pragma unroll
        for (int rt = 0; rt < 4; ++rt)
            #pragma unroll
            for (int r = 0; r < 4; ++r)
                ps[rt][r] += __shfl_xor(ps[rt][r], m);

    if ((lane & 15) == 0) {
        int rb = wr * 64 + (lane >> 4) * 4;
        #pragma unroll
        for (int rt = 0; rt < 4; ++rt)
            #pragma unroll
            for (int r = 0; r < 4; ++r)
                Ps[wc][rb + rt * 16 + r] = ps[rt][r];
    }
    __syncthreads();
    if (tid < 128) {
        int p = p0 + tid;
        if (p < NP) {
            float z = Ps[0][tid] + Ps[1][tid] + Ps[2][tid] + Ps[3][tid] + b_out[0];
            g[p] = fmaxf(z, 0.0f) + log1pf(expf(-fabsf(z)));
        }
    }
}

extern "C" void kernel_launch(void* const* d_in, const int* in_sizes, int n_in,
                              void* d_out, int out_size, void* d_ws, size_t ws_size,
                              hipStream_t stream) {
    const float* beta   = (const float*)d_in[0];
    const float* degree = (const float*)d_in[1];
    const int*   A_rows = (const int*)d_in[2];
    const int*   A_cols = (const int*)d_in[3];
    const float* A_vals = (const float*)d_in[4];
    const float* W_in   = (const float*)d_in[5];
    const float* b_in   = (const float*)d_in[6];
    const float* W_mp1  = (const float*)d_in[7];
    const float* W_mp2  = (const float*)d_in[8];
    const float* W_out  = (const float*)d_in[9];
    const float* b_out  = (const float*)d_in[10];
    float* g = (float*)d_out;

    char* ws = (char*)d_ws;
    unsigned short* AH  = (unsigned short*)(ws + OFF_AH);
    unsigned short* A2H = (unsigned short*)(ws + OFF_A2H);
    unsigned short* Bp  = (unsigned short*)(ws + OFF_BP);
    int*    cnt = (int*)(ws + OFF_CNT);
    float2* pc  = (float2*)(ws + OFF_PC);
    int2*   ev  = (int2*)(ws + OFF_EV);

    hipMemsetAsync(cnt, 0, NP * sizeof(int), stream);

    bp_kernel<<<512, 256, 0, stream>>>(W_mp1, W_mp2, Bp);
    pc_kernel<<<(NP + 255) / 256, 256, 0, stream>>>(beta, degree, pc);

    // XCD-sliced ELL scatter: slice = blockIdx % 8, 256 blocks per slice
    scatter_sliced<<<NSLICE * BPS, 256, 0, stream>>>(A_rows, A_cols, A_vals, cnt, ev);

    // AH = A @ relu(x W_in^T + b_in)   (h recomputed per edge)
    spmm_embed_kernel<<<(NP + 3) / 4, 256, 0, stream>>>(cnt, ev, pc, W_in, b_in, AH);
    // A2H = A @ AH
    spmm_gather_kernel<<<(NP + 3) / 4, 256, 0, stream>>>(cnt, ev, AH, A2H);

    mp_out_kernel<<<(NP + 127) / 128, 512, 0, stream>>>(AH, A2H, Bp, W_out, b_out, g);
}